// Round 1
// baseline (170.073 us; speedup 1.0000x reference)
//
#include <hip/hip_runtime.h>

#define F_XS 10
#define F_XT 5
#define F_E  10
#define F_U  10
#define F_IN 35
#define WPAD 12   // pad weight rows 10 -> 12 floats so rows are 48B (16B-aligned) for float4 reads

__global__ __launch_bounds__(256) void edge_model_kernel(
    const float* __restrict__ x_s,
    const float* __restrict__ x_t,
    const int* __restrict__ src,
    const int* __restrict__ tgt,
    const float* __restrict__ edge_attr,
    const float* __restrict__ u,
    const int* __restrict__ batch_e,
    const float* __restrict__ W1,
    const float* __restrict__ b1,
    const float* __restrict__ W2,
    const float* __restrict__ b2,
    float* __restrict__ out,
    int E)
{
    __shared__ float sW1[F_IN * WPAD];   // 35 x 12
    __shared__ float sW2[F_E * WPAD];    // 10 x 12
    __shared__ float sb1[F_E];
    __shared__ float sb2[F_E];
    __shared__ float sU[16 * F_U];       // B=16 graphs

    const int t = threadIdx.x;
    for (int i = t; i < F_IN * F_E; i += 256) sW1[(i / 10) * WPAD + (i % 10)] = W1[i];
    for (int i = t; i < F_E * F_E; i += 256)  sW2[(i / 10) * WPAD + (i % 10)] = W2[i];
    if (t < F_E) { sb1[t] = b1[t]; sb2[t] = b2[t]; }
    for (int i = t; i < 16 * F_U; i += 256) sU[i] = u[i];
    __syncthreads();

    const int e = blockIdx.x * 256 + t;
    if (e >= E) return;

    // ---- gather 35 input features ----
    float f[F_IN];
    {
        const float* ps = x_s + (size_t)src[e] * F_XS;   // rows are 40B -> 8B aligned
        #pragma unroll
        for (int i = 0; i < 5; ++i) {
            float2 v = *(const float2*)(ps + 2 * i);
            f[2 * i] = v.x; f[2 * i + 1] = v.y;
        }
        const float* pt = x_t + (size_t)tgt[e] * F_XT;   // rows are 20B -> only 4B aligned
        #pragma unroll
        for (int i = 0; i < F_XT; ++i) f[F_XS + i] = pt[i];

        const float* pe = edge_attr + (size_t)e * F_E;   // rows are 40B -> 8B aligned
        #pragma unroll
        for (int i = 0; i < 5; ++i) {
            float2 v = *(const float2*)(pe + 2 * i);
            f[15 + 2 * i] = v.x; f[15 + 2 * i + 1] = v.y;
        }
        const float* pu = sU + batch_e[e] * F_U;         // LDS, 8B aligned (40B rows)
        #pragma unroll
        for (int i = 0; i < 5; ++i) {
            float2 v = *(const float2*)(pu + 2 * i);
            f[25 + 2 * i] = v.x; f[25 + 2 * i + 1] = v.y;
        }
    }

    // ---- layer 1: h = f @ W1 + b1 ----
    float h[F_E];
    #pragma unroll
    for (int j = 0; j < F_E; ++j) h[j] = sb1[j];
    #pragma unroll
    for (int k = 0; k < F_IN; ++k) {
        const float fk = f[k];
        const float4 wa = *(const float4*)&sW1[k * WPAD];
        const float4 wb = *(const float4*)&sW1[k * WPAD + 4];
        const float2 wc = *(const float2*)&sW1[k * WPAD + 8];
        h[0] += fk * wa.x; h[1] += fk * wa.y; h[2] += fk * wa.z; h[3] += fk * wa.w;
        h[4] += fk * wb.x; h[5] += fk * wb.y; h[6] += fk * wb.z; h[7] += fk * wb.w;
        h[8] += fk * wc.x; h[9] += fk * wc.y;
    }
    // LeakyReLU(0.1)
    #pragma unroll
    for (int j = 0; j < F_E; ++j) h[j] = (h[j] >= 0.f) ? h[j] : 0.1f * h[j];

    // ---- layer 2: o = h @ W2 + b2 ----
    float o[F_E];
    #pragma unroll
    for (int j = 0; j < F_E; ++j) o[j] = sb2[j];
    #pragma unroll
    for (int k = 0; k < F_E; ++k) {
        const float hk = h[k];
        const float4 wa = *(const float4*)&sW2[k * WPAD];
        const float4 wb = *(const float4*)&sW2[k * WPAD + 4];
        const float2 wc = *(const float2*)&sW2[k * WPAD + 8];
        o[0] += hk * wa.x; o[1] += hk * wa.y; o[2] += hk * wa.z; o[3] += hk * wa.w;
        o[4] += hk * wb.x; o[5] += hk * wb.y; o[6] += hk * wb.z; o[7] += hk * wb.w;
        o[8] += hk * wc.x; o[9] += hk * wc.y;
    }

    // ---- store 10 floats ----
    float* po = out + (size_t)e * F_E;
    #pragma unroll
    for (int i = 0; i < 5; ++i) {
        float2 v; v.x = o[2 * i]; v.y = o[2 * i + 1];
        *(float2*)(po + 2 * i) = v;
    }
}

extern "C" void kernel_launch(void* const* d_in, const int* in_sizes, int n_in,
                              void* d_out, int out_size, void* d_ws, size_t ws_size,
                              hipStream_t stream) {
    const float* x_s      = (const float*)d_in[0];
    const float* x_t      = (const float*)d_in[1];
    const int*   ei       = (const int*)d_in[2];    // (2, E) flat: [src | tgt]
    const float* edge_att = (const float*)d_in[3];
    const float* u        = (const float*)d_in[4];
    const int*   batch_e  = (const int*)d_in[5];
    const float* W1       = (const float*)d_in[6];
    const float* b1       = (const float*)d_in[7];
    const float* W2       = (const float*)d_in[8];
    const float* b2       = (const float*)d_in[9];
    float* out = (float*)d_out;

    const int E = in_sizes[5];                      // batch_e has E elements
    const int blocks = (E + 255) / 256;
    edge_model_kernel<<<blocks, 256, 0, stream>>>(
        x_s, x_t, ei, ei + E, edge_att, u, batch_e,
        W1, b1, W2, b2, out, E);
}